// Round 17
// baseline (268.128 us; speedup 1.0000x reference)
//
#include <hip/hip_runtime.h>
#include <hip/hip_fp16.h>

#define N_NODES 100000
#define FEAT_IN 512
#define C1 16
#define C2 32
#define NEDGE 3200000
#define B_DDI 4096
#define F_DDI 1056

#define NBUCK 196          // 512-node dst buckets
#define CAP_BUCK 32768     // fixed bucket capacity (mean 16327, sd 128 -> +128 sigma)
#define BIN_C 6144         // edges per k_bin block chunk (31KB LDS -> ~5 blocks/CU)
#define NB_BIN ((NEDGE + BIN_C - 1) / BIN_C)   // 521
#define PB_CAP 12288       // k_place scat capacity per half (ints)

typedef float f4v __attribute__((ext_vector_type(4)));
typedef float f8v __attribute__((ext_vector_type(8)));
typedef _Float16 h4v __attribute__((ext_vector_type(4)));
typedef _Float16 h8v __attribute__((ext_vector_type(8)));

// workspace offsets (bytes); ws ~819MB, no aliasing
#define O_DINV   0u           // N floats
#define O_RP2    524288u      // 2N+1 ints
#define O_COL    1572864u     // E ints (CSR src)
#define O_GBUF   16777216u    // NBUCK*CAP_BUCK uints (25.7MB)
#define O_H1     46137344u    // N*16 halves (dinv-prescaled h1, fp16 -> L2-resident)
#define O_OUT1   54525952u    // N*16 halves (dinv-prescaled out1, fp16)
#define O_GCUR   71303168u    // NBUCK ints (bucket edge counts)

// ---------------- bucket build ----------------

// multisplit into 196 dst-buckets at fixed bases; stores lane-contiguous via LDS.
// gcur is zero-initialized by memset; holds per-bucket used counts.
__global__ __launch_bounds__(256) void k_bin(const int* __restrict__ ei,
                                             int* __restrict__ gcur,
                                             unsigned int* __restrict__ gbuf) {
    __shared__ int lcnt[256];
    __shared__ int lscan[256];
    __shared__ int lbase[256];
    __shared__ unsigned int sdat[BIN_C];
    __shared__ unsigned char sb[BIN_C];
    int tid = threadIdx.x;
    int e0 = blockIdx.x * BIN_C;

    lcnt[tid] = 0;
    __syncthreads();
    #pragma unroll 4
    for (int j = 0; j < BIN_C / 256; ++j) {
        int e = e0 + j * 256 + tid;
        if (e < NEDGE) atomicAdd(&lcnt[ei[NEDGE + e] >> 9], 1);
    }
    __syncthreads();
    lscan[tid] = lcnt[tid];
    __syncthreads();
    for (int off = 1; off < 256; off <<= 1) {
        int t = (tid >= off) ? lscan[tid - off] : 0;
        __syncthreads();
        lscan[tid] += t;
        __syncthreads();
    }
    lscan[tid] -= lcnt[tid];   // exclusive
    if (tid < NBUCK) lbase[tid] = tid * CAP_BUCK + atomicAdd(&gcur[tid], lcnt[tid]);
    __syncthreads();
    lcnt[tid] = 0;
    __syncthreads();
    #pragma unroll 4
    for (int j = 0; j < BIN_C / 256; ++j) {
        int e = e0 + j * 256 + tid;
        if (e < NEDGE) {
            int s = ei[e];
            int d = ei[NEDGE + e];
            int b = d >> 9;
            int p = lscan[b] + atomicAdd(&lcnt[b], 1);
            sdat[p] = (unsigned int)s | ((unsigned int)(d & 511) << 17);
            sb[p] = (unsigned char)b;
        }
    }
    __syncthreads();
    int tot = (e0 + BIN_C <= NEDGE) ? BIN_C : (NEDGE - e0);
    for (int i = tid; i < tot; i += 256) {
        int b = sb[i];
        gbuf[lbase[b] + (i - lscan[b])] = sdat[i];
    }
}

// per bucket: local prefix over gcur -> dense base; count per node -> scan
// -> rp2/dinv; place edges via LDS stage (two node-half rounds), coalesced flush.
__global__ __launch_bounds__(512) void k_place(const int* __restrict__ gcur,
                                               const unsigned int* __restrict__ gbuf,
                                               int* __restrict__ col,
                                               int* __restrict__ rp2,
                                               float* __restrict__ dinv) {
    __shared__ int scat[PB_CAP];
    __shared__ int pre[256];
    __shared__ int cnt[512];
    __shared__ int sc[512];
    __shared__ int lcur[512];
    int b = blockIdx.x;
    int tid = threadIdx.x;

    // block-local exclusive prefix of bucket counts
    if (tid < 256) pre[tid] = (tid < NBUCK) ? gcur[tid] : 0;
    __syncthreads();
    for (int off = 1; off < 256; off <<= 1) {
        int t = 0;
        if (tid < 256 && tid >= off) t = pre[tid - off];
        __syncthreads();
        if (tid < 256) pre[tid] += t;
        __syncthreads();
    }
    int Eb = gcur[b];
    int begc = pre[b] - Eb;          // exclusive prefix
    if (b == NBUCK - 1 && tid == 0) rp2[2 * N_NODES] = NEDGE;
    const unsigned int* __restrict__ gb = gbuf + ((size_t)b << 15);
    int n0 = b * 512;

    cnt[tid] = 0;
    __syncthreads();
    for (int i = tid; i < Eb; i += 512)
        atomicAdd(&cnt[gb[i] >> 17], 1);
    __syncthreads();
    int deg = cnt[tid];
    sc[tid] = deg;
    __syncthreads();
    for (int off = 1; off < 512; off <<= 1) {
        int t = (tid >= off) ? sc[tid - off] : 0;
        __syncthreads();
        sc[tid] += t;
        __syncthreads();
    }
    int ex = sc[tid] - deg;
    lcur[tid] = ex;
    int n = n0 + tid;
    if (n < N_NODES) {
        rp2[2 * n] = begc + ex;
        rp2[2 * n + 1] = begc + ex;   // unused mid-split (kept for layout compat)
        dinv[n] = rsqrtf((float)deg + 1.0f);
    }
    __syncthreads();
    int h0 = sc[255];

    if (h0 <= PB_CAP && (Eb - h0) <= PB_CAP) {
        for (int i = tid; i < Eb; i += 512) {
            unsigned int u = gb[i];
            int dl = (int)(u >> 17);
            if (dl < 256) {
                int p = atomicAdd(&lcur[dl], 1);
                scat[p] = (int)(u & 0x1FFFFu);
            }
        }
        __syncthreads();
        for (int i = tid; i < h0; i += 512) col[begc + i] = scat[i];
        __syncthreads();
        for (int i = tid; i < Eb; i += 512) {
            unsigned int u = gb[i];
            int dl = (int)(u >> 17);
            if (dl >= 256) {
                int p = atomicAdd(&lcur[dl], 1);
                scat[p - h0] = (int)(u & 0x1FFFFu);
            }
        }
        __syncthreads();
        for (int i = tid; i < Eb - h0; i += 512) col[begc + h0 + i] = scat[i];
    } else {
        // statistically-unreachable fallback: direct scatter
        for (int i = tid; i < Eb; i += 512) {
            unsigned int u = gb[i];
            int p = atomicAdd(&lcur[u >> 17], 1);
            col[begc + p] = (int)(u & 0x1FFFFu);
        }
    }
}

// ---------------- GEMM1: h1s = fp16( dinv * (x @ W1) ), barrier-free streaming ----

__global__ __launch_bounds__(256) void k_gemm1(const float* __restrict__ x,
                                               const float* __restrict__ W1,
                                               const float* __restrict__ dinv,
                                               _Float16* __restrict__ h1s) {
    __shared__ float part[4][64][17];
    int tid = threadIdx.x;
    int wv = __builtin_amdgcn_readfirstlane(tid >> 6);   // wave-uniform
    int lane = tid & 63;
    int row = blockIdx.x * 64 + lane;
    int crow = row < N_NODES ? row : N_NODES - 1;
    const float* __restrict__ xr = x + (size_t)crow * FEAT_IN + wv * 128;

    float acc[16];
    #pragma unroll
    for (int c = 0; c < 16; ++c) acc[c] = 0.f;

    for (int it = 0; it < 8; ++it) {
        const float4* xp = reinterpret_cast<const float4*>(xr + it * 16);
        float4 xv0 = xp[0], xv1 = xp[1], xv2 = xp[2], xv3 = xp[3];
        float xs[16] = {xv0.x, xv0.y, xv0.z, xv0.w, xv1.x, xv1.y, xv1.z, xv1.w,
                        xv2.x, xv2.y, xv2.z, xv2.w, xv3.x, xv3.y, xv3.z, xv3.w};
        int kb = wv * 128 + it * 16;
        #pragma unroll
        for (int j = 0; j < 16; ++j) {
            const float* __restrict__ wr = W1 + (size_t)(kb + j) * 16;  // uniform addr
            #pragma unroll
            for (int c = 0; c < 16; ++c) acc[c] = fmaf(xs[j], wr[c], acc[c]);
        }
    }
    #pragma unroll
    for (int c = 0; c < 16; ++c) part[wv][lane][c] = acc[c];
    __syncthreads();

    int r2 = tid >> 2, cq = tid & 3;
    int grow = blockIdx.x * 64 + r2;
    if (grow < N_NODES) {
        float dv = dinv[grow];
        f4v o;
        #pragma unroll
        for (int j = 0; j < 4; ++j) {
            int c = cq * 4 + j;
            o[j] = dv * (part[0][r2][c] + part[1][r2][c] + part[2][r2][c] + part[3][r2][c]);
        }
        h4v oh = __builtin_convertvector(o, h4v);
        *reinterpret_cast<h4v*>(&h1s[(size_t)grow * C1 + cq * 4]) = oh;
    }
}

// ---------------- fused full-row gathers: 2 lanes/node, fp16x8 (16B) loads ----

// layer-1: out1s = fp16( dinv * relu( di*(acc + h1s[node]) + b1 ) )
__global__ __launch_bounds__(256) void k_gather1(const int* __restrict__ rp2, const int* __restrict__ col,
                                                 const float* __restrict__ dinv, const _Float16* __restrict__ h1s,
                                                 const float* __restrict__ b1, _Float16* __restrict__ out1s) {
    int t = blockIdx.x * 256 + threadIdx.x;
    int node = t >> 1;
    int q = t & 1;
    if (node >= N_NODES) return;
    int beg = rp2[2 * node], end = rp2[2 * node + 2];
    f8v acc = {0.f, 0.f, 0.f, 0.f, 0.f, 0.f, 0.f, 0.f};
    int p = beg;
    while (p < end && (p & 3)) {
        int s = col[p++];
        h8v h = *reinterpret_cast<const h8v*>(&h1s[s * C1 + q * 8]);
        acc += __builtin_convertvector(h, f8v);
    }
    for (; p + 7 < end; p += 8) {
        int4 sa = *reinterpret_cast<const int4*>(&col[p]);
        int4 sb = *reinterpret_cast<const int4*>(&col[p + 4]);
        h8v v0 = *reinterpret_cast<const h8v*>(&h1s[sa.x * C1 + q * 8]);
        h8v v1 = *reinterpret_cast<const h8v*>(&h1s[sa.y * C1 + q * 8]);
        h8v v2 = *reinterpret_cast<const h8v*>(&h1s[sa.z * C1 + q * 8]);
        h8v v3 = *reinterpret_cast<const h8v*>(&h1s[sa.w * C1 + q * 8]);
        h8v v4 = *reinterpret_cast<const h8v*>(&h1s[sb.x * C1 + q * 8]);
        h8v v5 = *reinterpret_cast<const h8v*>(&h1s[sb.y * C1 + q * 8]);
        h8v v6 = *reinterpret_cast<const h8v*>(&h1s[sb.z * C1 + q * 8]);
        h8v v7 = *reinterpret_cast<const h8v*>(&h1s[sb.w * C1 + q * 8]);
        f8v a0 = __builtin_convertvector(v0, f8v) + __builtin_convertvector(v1, f8v);
        f8v a1 = __builtin_convertvector(v2, f8v) + __builtin_convertvector(v3, f8v);
        f8v a2 = __builtin_convertvector(v4, f8v) + __builtin_convertvector(v5, f8v);
        f8v a3 = __builtin_convertvector(v6, f8v) + __builtin_convertvector(v7, f8v);
        acc += (a0 + a1) + (a2 + a3);
    }
    for (; p + 3 < end; p += 4) {
        int4 sa = *reinterpret_cast<const int4*>(&col[p]);
        h8v v0 = *reinterpret_cast<const h8v*>(&h1s[sa.x * C1 + q * 8]);
        h8v v1 = *reinterpret_cast<const h8v*>(&h1s[sa.y * C1 + q * 8]);
        h8v v2 = *reinterpret_cast<const h8v*>(&h1s[sa.z * C1 + q * 8]);
        h8v v3 = *reinterpret_cast<const h8v*>(&h1s[sa.w * C1 + q * 8]);
        acc += (__builtin_convertvector(v0, f8v) + __builtin_convertvector(v1, f8v))
             + (__builtin_convertvector(v2, f8v) + __builtin_convertvector(v3, f8v));
    }
    for (; p < end; ++p) {
        int s = col[p];
        h8v h = *reinterpret_cast<const h8v*>(&h1s[s * C1 + q * 8]);
        acc += __builtin_convertvector(h, f8v);
    }
    float di = dinv[node];
    h8v hsh = *reinterpret_cast<const h8v*>(&h1s[node * C1 + q * 8]);
    f8v hs = __builtin_convertvector(hsh, f8v);
    f8v bv = *reinterpret_cast<const f8v*>(&b1[q * 8]);
    f8v v = di * (acc + hs) + bv;
    f8v z = {0.f, 0.f, 0.f, 0.f, 0.f, 0.f, 0.f, 0.f};
    f8v r = v > z ? v : z;
    r = di * r;
    *reinterpret_cast<h8v*>(&out1s[node * C1 + q * 8]) = __builtin_convertvector(r, h8v);
}

// layer-2: full-row gather fused with @W2+b2+relu -> d_out (ppi)
// 128 nodes/block, 2 lanes/node; each lane computes 16 of the 32 outputs.
__global__ __launch_bounds__(256) void k_gather2(const int* __restrict__ rp2, const int* __restrict__ col,
                                                 const float* __restrict__ dinv, const _Float16* __restrict__ out1s,
                                                 const float* __restrict__ W2, const float* __restrict__ b2,
                                                 float* __restrict__ out) {
    __shared__ float sacc[128][17];
    __shared__ float sW[16 * 32];
    __shared__ float sb2[32];
    int tid = threadIdx.x;
    if (tid < 128)
        *reinterpret_cast<float4*>(&sW[tid * 4]) = *reinterpret_cast<const float4*>(&W2[tid * 4]);
    if (tid < 32) sb2[tid] = b2[tid];
    int g = tid >> 1;
    int q = tid & 1;
    int nodeRaw = blockIdx.x * 128 + g;
    int node = nodeRaw < N_NODES ? nodeRaw : N_NODES - 1;
    int beg = rp2[2 * node], end = rp2[2 * node + 2];
    f8v acc = {0.f, 0.f, 0.f, 0.f, 0.f, 0.f, 0.f, 0.f};
    int p = beg;
    while (p < end && (p & 3)) {
        int s = col[p++];
        h8v h = *reinterpret_cast<const h8v*>(&out1s[s * C1 + q * 8]);
        acc += __builtin_convertvector(h, f8v);
    }
    for (; p + 7 < end; p += 8) {
        int4 sa = *reinterpret_cast<const int4*>(&col[p]);
        int4 sb = *reinterpret_cast<const int4*>(&col[p + 4]);
        h8v v0 = *reinterpret_cast<const h8v*>(&out1s[sa.x * C1 + q * 8]);
        h8v v1 = *reinterpret_cast<const h8v*>(&out1s[sa.y * C1 + q * 8]);
        h8v v2 = *reinterpret_cast<const h8v*>(&out1s[sa.z * C1 + q * 8]);
        h8v v3 = *reinterpret_cast<const h8v*>(&out1s[sa.w * C1 + q * 8]);
        h8v v4 = *reinterpret_cast<const h8v*>(&out1s[sb.x * C1 + q * 8]);
        h8v v5 = *reinterpret_cast<const h8v*>(&out1s[sb.y * C1 + q * 8]);
        h8v v6 = *reinterpret_cast<const h8v*>(&out1s[sb.z * C1 + q * 8]);
        h8v v7 = *reinterpret_cast<const h8v*>(&out1s[sb.w * C1 + q * 8]);
        f8v a0 = __builtin_convertvector(v0, f8v) + __builtin_convertvector(v1, f8v);
        f8v a1 = __builtin_convertvector(v2, f8v) + __builtin_convertvector(v3, f8v);
        f8v a2 = __builtin_convertvector(v4, f8v) + __builtin_convertvector(v5, f8v);
        f8v a3 = __builtin_convertvector(v6, f8v) + __builtin_convertvector(v7, f8v);
        acc += (a0 + a1) + (a2 + a3);
    }
    for (; p + 3 < end; p += 4) {
        int4 sa = *reinterpret_cast<const int4*>(&col[p]);
        h8v v0 = *reinterpret_cast<const h8v*>(&out1s[sa.x * C1 + q * 8]);
        h8v v1 = *reinterpret_cast<const h8v*>(&out1s[sa.y * C1 + q * 8]);
        h8v v2 = *reinterpret_cast<const h8v*>(&out1s[sa.z * C1 + q * 8]);
        h8v v3 = *reinterpret_cast<const h8v*>(&out1s[sa.w * C1 + q * 8]);
        acc += (__builtin_convertvector(v0, f8v) + __builtin_convertvector(v1, f8v))
             + (__builtin_convertvector(v2, f8v) + __builtin_convertvector(v3, f8v));
    }
    for (; p < end; ++p) {
        int s = col[p];
        h8v h = *reinterpret_cast<const h8v*>(&out1s[s * C1 + q * 8]);
        acc += __builtin_convertvector(h, f8v);
    }
    float di = dinv[node];
    h8v hsh = *reinterpret_cast<const h8v*>(&out1s[node * C1 + q * 8]);
    f8v hs = __builtin_convertvector(hsh, f8v);
    f8v v = di * (acc + hs);
    #pragma unroll
    for (int j = 0; j < 8; ++j) sacc[g][q * 8 + j] = v[j];
    __syncthreads();
    float r[16];
    #pragma unroll
    for (int j = 0; j < 16; ++j) r[j] = sb2[q * 16 + j];
    #pragma unroll
    for (int k = 0; k < 16; ++k) {
        float a = sacc[g][k];
        const float* wrow = &sW[k * 32 + q * 16];
        #pragma unroll
        for (int j = 0; j < 16; ++j) r[j] = fmaf(a, wrow[j], r[j]);
    }
    if (nodeRaw < N_NODES) {
        float* op = &out[(size_t)nodeRaw * C2 + q * 16];
        #pragma unroll
        for (int j = 0; j < 16; j += 4) {
            f4v o = {r[j], r[j+1], r[j+2], r[j+3]};
            f4v z = {0.f, 0.f, 0.f, 0.f};
            o = o > z ? o : z;
            *reinterpret_cast<f4v*>(&op[j]) = o;
        }
    }
}

// ---------------- DDI branch (round-10 proven form: 4 rows/block) ----------------

#define DDI_CHUNK 132   // 1056 = 8 * 132

__global__ __launch_bounds__(256) void k_ddi(const float* __restrict__ feat,
                                             const float* __restrict__ fW1, const float* __restrict__ fb1,
                                             const float* __restrict__ fW2, const float* __restrict__ fb2,
                                             const float* __restrict__ fW3, const float* __restrict__ fb3,
                                             float* __restrict__ out) {
    __shared__ float sW[DDI_CHUNK * 64];
    __shared__ float sH[4][64];
    int tid = threadIdx.x;
    int wave = tid >> 6;
    int lane = tid & 63;
    int row = blockIdx.x * 4 + wave;

    float acc = 0.f;
    for (int k0 = 0; k0 < F_DDI; k0 += DDI_CHUNK) {
        __syncthreads();
        for (int idx = tid; idx < DDI_CHUNK * 64; idx += 256)
            sW[idx] = fW1[k0 * 64 + idx];
        __syncthreads();
        const float* frow = &feat[(size_t)row * F_DDI + k0];
        #pragma unroll 4
        for (int kk = 0; kk < DDI_CHUNK; kk += 4) {
            float4 fv = *reinterpret_cast<const float4*>(&frow[kk]);
            acc += fv.x * sW[(kk + 0) * 64 + lane];
            acc += fv.y * sW[(kk + 1) * 64 + lane];
            acc += fv.z * sW[(kk + 2) * 64 + lane];
            acc += fv.w * sW[(kk + 3) * 64 + lane];
        }
    }
    float h = fmaxf(acc + fb1[lane], 0.f);
    __syncthreads();
    sH[wave][lane] = h;
    __syncthreads();

    int c16 = lane & 15;
    float acc2 = 0.f;
    #pragma unroll
    for (int kk = 0; kk < 64; ++kk)
        acc2 += sH[wave][kk] * fW2[kk * 16 + c16];
    float o2 = fmaxf(acc2 + fb2[c16], 0.f);
    float part = o2 * fW3[c16];
    #pragma unroll
    for (int off = 8; off >= 1; off >>= 1)
        part += __shfl_xor(part, off, 16);
    if (lane == 0)
        out[row] = fmaxf(part + fb3[0], 0.f);
}

// ---------------- launch ----------------

extern "C" void kernel_launch(void* const* d_in, const int* in_sizes, int n_in,
                              void* d_out, int out_size, void* d_ws, size_t ws_size,
                              hipStream_t stream) {
    const float* x   = (const float*)d_in[0];
    const int*   ei  = (const int*)d_in[1];
    const float* ddi = (const float*)d_in[2];
    const float* W1  = (const float*)d_in[3];
    const float* b1  = (const float*)d_in[4];
    const float* W2  = (const float*)d_in[5];
    const float* b2  = (const float*)d_in[6];
    const float* fW1 = (const float*)d_in[7];
    const float* fb1 = (const float*)d_in[8];
    const float* fW2 = (const float*)d_in[9];
    const float* fb2 = (const float*)d_in[10];
    const float* fW3 = (const float*)d_in[11];
    const float* fb3 = (const float*)d_in[12];

    char* ws = (char*)d_ws;
    float* dinv  = (float*)(ws + O_DINV);
    int*   rp2   = (int*)(ws + O_RP2);
    int*   col   = (int*)(ws + O_COL);
    unsigned int* gbuf = (unsigned int*)(ws + O_GBUF);
    _Float16* h1s   = (_Float16*)(ws + O_H1);
    _Float16* out1s = (_Float16*)(ws + O_OUT1);
    int*   gcur  = (int*)(ws + O_GCUR);

    float* out_ppi = (float*)d_out;
    float* out_ddi = out_ppi + (size_t)N_NODES * C2;

    hipMemsetAsync(gcur, 0, NBUCK * sizeof(int), stream);
    k_bin<<<NB_BIN, 256, 0, stream>>>(ei, gcur, gbuf);
    k_place<<<NBUCK, 512, 0, stream>>>(gcur, gbuf, col, rp2, dinv);

    k_gemm1<<<(N_NODES + 63) / 64, 256, 0, stream>>>(x, W1, dinv, h1s);

    k_gather1<<<(N_NODES * 2 + 255) / 256, 256, 0, stream>>>(rp2, col, dinv, h1s, b1, out1s);
    k_gather2<<<(N_NODES + 127) / 128, 256, 0, stream>>>(rp2, col, dinv, out1s, W2, b2, out_ppi);

    k_ddi<<<B_DDI / 4, 256, 0, stream>>>(ddi, fW1, fb1, fW2, fb2, fW3, fb3, out_ddi);
}

// Round 18
// 260.335 us; speedup vs baseline: 1.0299x; 1.0299x over previous
//
#include <hip/hip_runtime.h>
#include <hip/hip_fp16.h>

#define N_NODES 100000
#define FEAT_IN 512
#define C1 16
#define C2 32
#define NEDGE 3200000
#define B_DDI 4096
#define F_DDI 1056

#define NBUCK 196          // 512-node dst buckets
#define CAP_BUCK 32768     // fixed bucket capacity (mean 16327, sd 128 -> +128 sigma)
#define BIN_C 6144         // edges per k_bin block chunk (31KB LDS -> ~5 blocks/CU)
#define NB_BIN ((NEDGE + BIN_C - 1) / BIN_C)   // 521
#define PB_CAP 12288       // k_place scat capacity per half (ints)

typedef float f4v __attribute__((ext_vector_type(4)));
typedef _Float16 h4v __attribute__((ext_vector_type(4)));

// workspace offsets (bytes); ws ~819MB, no aliasing
#define O_DINV   0u           // N floats
#define O_RP2    524288u      // 2N+1 ints
#define O_COL    1572864u     // E ints (CSR src)
#define O_GBUF   16777216u    // NBUCK*CAP_BUCK uints (25.7MB)
#define O_H1     46137344u    // N*16 halves (dinv-prescaled h1, fp16 -> L2-resident)
#define O_OUT1   54525952u    // N*16 halves (dinv-prescaled out1, fp16)
#define O_GCUR   71303168u    // NBUCK ints (bucket edge counts)

// ---------------- bucket build ----------------

// multisplit into 196 dst-buckets at fixed bases; stores lane-contiguous via LDS.
// gcur is zero-initialized by memset; holds per-bucket used counts.
__global__ __launch_bounds__(256) void k_bin(const int* __restrict__ ei,
                                             int* __restrict__ gcur,
                                             unsigned int* __restrict__ gbuf) {
    __shared__ int lcnt[256];
    __shared__ int lscan[256];
    __shared__ int lbase[256];
    __shared__ unsigned int sdat[BIN_C];
    __shared__ unsigned char sb[BIN_C];
    int tid = threadIdx.x;
    int e0 = blockIdx.x * BIN_C;

    lcnt[tid] = 0;
    __syncthreads();
    #pragma unroll 4
    for (int j = 0; j < BIN_C / 256; ++j) {
        int e = e0 + j * 256 + tid;
        if (e < NEDGE) atomicAdd(&lcnt[ei[NEDGE + e] >> 9], 1);
    }
    __syncthreads();
    lscan[tid] = lcnt[tid];
    __syncthreads();
    for (int off = 1; off < 256; off <<= 1) {
        int t = (tid >= off) ? lscan[tid - off] : 0;
        __syncthreads();
        lscan[tid] += t;
        __syncthreads();
    }
    lscan[tid] -= lcnt[tid];   // exclusive
    if (tid < NBUCK) lbase[tid] = tid * CAP_BUCK + atomicAdd(&gcur[tid], lcnt[tid]);
    __syncthreads();
    lcnt[tid] = 0;
    __syncthreads();
    #pragma unroll 4
    for (int j = 0; j < BIN_C / 256; ++j) {
        int e = e0 + j * 256 + tid;
        if (e < NEDGE) {
            int s = ei[e];
            int d = ei[NEDGE + e];
            int b = d >> 9;
            int p = lscan[b] + atomicAdd(&lcnt[b], 1);
            sdat[p] = (unsigned int)s | ((unsigned int)(d & 511) << 17);
            sb[p] = (unsigned char)b;
        }
    }
    __syncthreads();
    int tot = (e0 + BIN_C <= NEDGE) ? BIN_C : (NEDGE - e0);
    for (int i = tid; i < tot; i += 256) {
        int b = sb[i];
        gbuf[lbase[b] + (i - lscan[b])] = sdat[i];
    }
}

// per bucket: local prefix over gcur -> dense base; count per node -> scan
// -> rp2/dinv; place edges via LDS stage (two node-half rounds), coalesced flush.
__global__ __launch_bounds__(512) void k_place(const int* __restrict__ gcur,
                                               const unsigned int* __restrict__ gbuf,
                                               int* __restrict__ col,
                                               int* __restrict__ rp2,
                                               float* __restrict__ dinv) {
    __shared__ int scat[PB_CAP];
    __shared__ int pre[256];
    __shared__ int cnt[512];
    __shared__ int sc[512];
    __shared__ int lcur[512];
    int b = blockIdx.x;
    int tid = threadIdx.x;

    // block-local exclusive prefix of bucket counts
    if (tid < 256) pre[tid] = (tid < NBUCK) ? gcur[tid] : 0;
    __syncthreads();
    for (int off = 1; off < 256; off <<= 1) {
        int t = 0;
        if (tid < 256 && tid >= off) t = pre[tid - off];
        __syncthreads();
        if (tid < 256) pre[tid] += t;
        __syncthreads();
    }
    int Eb = gcur[b];
    int begc = pre[b] - Eb;          // exclusive prefix
    if (b == NBUCK - 1 && tid == 0) rp2[2 * N_NODES] = NEDGE;
    const unsigned int* __restrict__ gb = gbuf + ((size_t)b << 15);
    int n0 = b * 512;

    cnt[tid] = 0;
    __syncthreads();
    for (int i = tid; i < Eb; i += 512)
        atomicAdd(&cnt[gb[i] >> 17], 1);
    __syncthreads();
    int deg = cnt[tid];
    sc[tid] = deg;
    __syncthreads();
    for (int off = 1; off < 512; off <<= 1) {
        int t = (tid >= off) ? sc[tid - off] : 0;
        __syncthreads();
        sc[tid] += t;
        __syncthreads();
    }
    int ex = sc[tid] - deg;
    lcur[tid] = ex;
    int n = n0 + tid;
    if (n < N_NODES) {
        rp2[2 * n] = begc + ex;
        rp2[2 * n + 1] = begc + ex;   // unused mid-split (kept for layout compat)
        dinv[n] = rsqrtf((float)deg + 1.0f);
    }
    __syncthreads();
    int h0 = sc[255];

    if (h0 <= PB_CAP && (Eb - h0) <= PB_CAP) {
        for (int i = tid; i < Eb; i += 512) {
            unsigned int u = gb[i];
            int dl = (int)(u >> 17);
            if (dl < 256) {
                int p = atomicAdd(&lcur[dl], 1);
                scat[p] = (int)(u & 0x1FFFFu);
            }
        }
        __syncthreads();
        for (int i = tid; i < h0; i += 512) col[begc + i] = scat[i];
        __syncthreads();
        for (int i = tid; i < Eb; i += 512) {
            unsigned int u = gb[i];
            int dl = (int)(u >> 17);
            if (dl >= 256) {
                int p = atomicAdd(&lcur[dl], 1);
                scat[p - h0] = (int)(u & 0x1FFFFu);
            }
        }
        __syncthreads();
        for (int i = tid; i < Eb - h0; i += 512) col[begc + h0 + i] = scat[i];
    } else {
        // statistically-unreachable fallback: direct scatter
        for (int i = tid; i < Eb; i += 512) {
            unsigned int u = gb[i];
            int p = atomicAdd(&lcur[u >> 17], 1);
            col[begc + p] = (int)(u & 0x1FFFFu);
        }
    }
}

// ---------------- GEMM1: h1s = fp16( dinv * (x @ W1) ), barrier-free streaming ----

__global__ __launch_bounds__(256) void k_gemm1(const float* __restrict__ x,
                                               const float* __restrict__ W1,
                                               const float* __restrict__ dinv,
                                               _Float16* __restrict__ h1s) {
    __shared__ float part[4][64][17];
    int tid = threadIdx.x;
    int wv = __builtin_amdgcn_readfirstlane(tid >> 6);   // wave-uniform
    int lane = tid & 63;
    int row = blockIdx.x * 64 + lane;
    int crow = row < N_NODES ? row : N_NODES - 1;
    const float* __restrict__ xr = x + (size_t)crow * FEAT_IN + wv * 128;

    float acc[16];
    #pragma unroll
    for (int c = 0; c < 16; ++c) acc[c] = 0.f;

    for (int it = 0; it < 8; ++it) {
        const float4* xp = reinterpret_cast<const float4*>(xr + it * 16);
        float4 xv0 = xp[0], xv1 = xp[1], xv2 = xp[2], xv3 = xp[3];
        float xs[16] = {xv0.x, xv0.y, xv0.z, xv0.w, xv1.x, xv1.y, xv1.z, xv1.w,
                        xv2.x, xv2.y, xv2.z, xv2.w, xv3.x, xv3.y, xv3.z, xv3.w};
        int kb = wv * 128 + it * 16;
        #pragma unroll
        for (int j = 0; j < 16; ++j) {
            const float* __restrict__ wr = W1 + (size_t)(kb + j) * 16;  // uniform addr
            #pragma unroll
            for (int c = 0; c < 16; ++c) acc[c] = fmaf(xs[j], wr[c], acc[c]);
        }
    }
    #pragma unroll
    for (int c = 0; c < 16; ++c) part[wv][lane][c] = acc[c];
    __syncthreads();

    int r2 = tid >> 2, cq = tid & 3;
    int grow = blockIdx.x * 64 + r2;
    if (grow < N_NODES) {
        float dv = dinv[grow];
        f4v o;
        #pragma unroll
        for (int j = 0; j < 4; ++j) {
            int c = cq * 4 + j;
            o[j] = dv * (part[0][r2][c] + part[1][r2][c] + part[2][r2][c] + part[3][r2][c]);
        }
        h4v oh = __builtin_convertvector(o, h4v);
        *reinterpret_cast<h4v*>(&h1s[(size_t)grow * C1 + cq * 4]) = oh;
    }
}

// ---------------- fused full-row gathers (fp16 prescaled tables, int4 idx loads) ----

// layer-1: out1s = fp16( dinv * relu( di*(acc + h1s[node]) + b1 ) )
__global__ __launch_bounds__(256) void k_gather1(const int* __restrict__ rp2, const int* __restrict__ col,
                                                 const float* __restrict__ dinv, const _Float16* __restrict__ h1s,
                                                 const float* __restrict__ b1, _Float16* __restrict__ out1s) {
    int t = blockIdx.x * 256 + threadIdx.x;
    int node = t >> 2;
    int q = t & 3;
    if (node >= N_NODES) return;
    int beg = rp2[2 * node], end = rp2[2 * node + 2];
    f4v acc = {0.f, 0.f, 0.f, 0.f};
    int p = beg;
    while (p < end && (p & 3)) {
        int s = col[p++];
        h4v h = *reinterpret_cast<const h4v*>(&h1s[s * C1 + q * 4]);
        acc += __builtin_convertvector(h, f4v);
    }
    for (; p + 7 < end; p += 8) {
        int4 sa = *reinterpret_cast<const int4*>(&col[p]);
        int4 sb = *reinterpret_cast<const int4*>(&col[p + 4]);
        h4v v0 = *reinterpret_cast<const h4v*>(&h1s[sa.x * C1 + q * 4]);
        h4v v1 = *reinterpret_cast<const h4v*>(&h1s[sa.y * C1 + q * 4]);
        h4v v2 = *reinterpret_cast<const h4v*>(&h1s[sa.z * C1 + q * 4]);
        h4v v3 = *reinterpret_cast<const h4v*>(&h1s[sa.w * C1 + q * 4]);
        h4v v4 = *reinterpret_cast<const h4v*>(&h1s[sb.x * C1 + q * 4]);
        h4v v5 = *reinterpret_cast<const h4v*>(&h1s[sb.y * C1 + q * 4]);
        h4v v6 = *reinterpret_cast<const h4v*>(&h1s[sb.z * C1 + q * 4]);
        h4v v7 = *reinterpret_cast<const h4v*>(&h1s[sb.w * C1 + q * 4]);
        f4v a0 = __builtin_convertvector(v0, f4v) + __builtin_convertvector(v1, f4v);
        f4v a1 = __builtin_convertvector(v2, f4v) + __builtin_convertvector(v3, f4v);
        f4v a2 = __builtin_convertvector(v4, f4v) + __builtin_convertvector(v5, f4v);
        f4v a3 = __builtin_convertvector(v6, f4v) + __builtin_convertvector(v7, f4v);
        acc += (a0 + a1) + (a2 + a3);
    }
    for (; p + 3 < end; p += 4) {
        int4 sa = *reinterpret_cast<const int4*>(&col[p]);
        h4v v0 = *reinterpret_cast<const h4v*>(&h1s[sa.x * C1 + q * 4]);
        h4v v1 = *reinterpret_cast<const h4v*>(&h1s[sa.y * C1 + q * 4]);
        h4v v2 = *reinterpret_cast<const h4v*>(&h1s[sa.z * C1 + q * 4]);
        h4v v3 = *reinterpret_cast<const h4v*>(&h1s[sa.w * C1 + q * 4]);
        acc += (__builtin_convertvector(v0, f4v) + __builtin_convertvector(v1, f4v))
             + (__builtin_convertvector(v2, f4v) + __builtin_convertvector(v3, f4v));
    }
    for (; p < end; ++p) {
        int s = col[p];
        h4v h = *reinterpret_cast<const h4v*>(&h1s[s * C1 + q * 4]);
        acc += __builtin_convertvector(h, f4v);
    }
    float di = dinv[node];
    h4v hsh = *reinterpret_cast<const h4v*>(&h1s[node * C1 + q * 4]);
    f4v hs = __builtin_convertvector(hsh, f4v);
    f4v bv = *reinterpret_cast<const f4v*>(&b1[q * 4]);
    f4v v = di * (acc + hs) + bv;
    f4v z = {0.f, 0.f, 0.f, 0.f};
    f4v r = v > z ? v : z;
    r = di * r;
    *reinterpret_cast<h4v*>(&out1s[node * C1 + q * 4]) = __builtin_convertvector(r, h4v);
}

// layer-2: full-row gather fused with @W2+b2+relu -> d_out (ppi)
__global__ __launch_bounds__(256) void k_gather2(const int* __restrict__ rp2, const int* __restrict__ col,
                                                 const float* __restrict__ dinv, const _Float16* __restrict__ out1s,
                                                 const float* __restrict__ W2, const float* __restrict__ b2,
                                                 float* __restrict__ out) {
    __shared__ float sacc[64][17];
    __shared__ float sW[16 * 32];
    __shared__ float sb2[32];
    int tid = threadIdx.x;
    if (tid < 128)
        *reinterpret_cast<float4*>(&sW[tid * 4]) = *reinterpret_cast<const float4*>(&W2[tid * 4]);
    if (tid < 32) sb2[tid] = b2[tid];
    int g = tid >> 2;
    int q = tid & 3;
    int nodeRaw = blockIdx.x * 64 + g;
    int node = nodeRaw < N_NODES ? nodeRaw : N_NODES - 1;
    int beg = rp2[2 * node], end = rp2[2 * node + 2];
    f4v acc = {0.f, 0.f, 0.f, 0.f};
    int p = beg;
    while (p < end && (p & 3)) {
        int s = col[p++];
        h4v h = *reinterpret_cast<const h4v*>(&out1s[s * C1 + q * 4]);
        acc += __builtin_convertvector(h, f4v);
    }
    for (; p + 7 < end; p += 8) {
        int4 sa = *reinterpret_cast<const int4*>(&col[p]);
        int4 sb = *reinterpret_cast<const int4*>(&col[p + 4]);
        h4v v0 = *reinterpret_cast<const h4v*>(&out1s[sa.x * C1 + q * 4]);
        h4v v1 = *reinterpret_cast<const h4v*>(&out1s[sa.y * C1 + q * 4]);
        h4v v2 = *reinterpret_cast<const h4v*>(&out1s[sa.z * C1 + q * 4]);
        h4v v3 = *reinterpret_cast<const h4v*>(&out1s[sa.w * C1 + q * 4]);
        h4v v4 = *reinterpret_cast<const h4v*>(&out1s[sb.x * C1 + q * 4]);
        h4v v5 = *reinterpret_cast<const h4v*>(&out1s[sb.y * C1 + q * 4]);
        h4v v6 = *reinterpret_cast<const h4v*>(&out1s[sb.z * C1 + q * 4]);
        h4v v7 = *reinterpret_cast<const h4v*>(&out1s[sb.w * C1 + q * 4]);
        f4v a0 = __builtin_convertvector(v0, f4v) + __builtin_convertvector(v1, f4v);
        f4v a1 = __builtin_convertvector(v2, f4v) + __builtin_convertvector(v3, f4v);
        f4v a2 = __builtin_convertvector(v4, f4v) + __builtin_convertvector(v5, f4v);
        f4v a3 = __builtin_convertvector(v6, f4v) + __builtin_convertvector(v7, f4v);
        acc += (a0 + a1) + (a2 + a3);
    }
    for (; p + 3 < end; p += 4) {
        int4 sa = *reinterpret_cast<const int4*>(&col[p]);
        h4v v0 = *reinterpret_cast<const h4v*>(&out1s[sa.x * C1 + q * 4]);
        h4v v1 = *reinterpret_cast<const h4v*>(&out1s[sa.y * C1 + q * 4]);
        h4v v2 = *reinterpret_cast<const h4v*>(&out1s[sa.z * C1 + q * 4]);
        h4v v3 = *reinterpret_cast<const h4v*>(&out1s[sa.w * C1 + q * 4]);
        acc += (__builtin_convertvector(v0, f4v) + __builtin_convertvector(v1, f4v))
             + (__builtin_convertvector(v2, f4v) + __builtin_convertvector(v3, f4v));
    }
    for (; p < end; ++p) {
        int s = col[p];
        h4v h = *reinterpret_cast<const h4v*>(&out1s[s * C1 + q * 4]);
        acc += __builtin_convertvector(h, f4v);
    }
    float di = dinv[node];
    h4v hsh = *reinterpret_cast<const h4v*>(&out1s[node * C1 + q * 4]);
    f4v hs = __builtin_convertvector(hsh, f4v);
    f4v v = di * (acc + hs);
    sacc[g][q * 4 + 0] = v.x;
    sacc[g][q * 4 + 1] = v.y;
    sacc[g][q * 4 + 2] = v.z;
    sacc[g][q * 4 + 3] = v.w;
    __syncthreads();
    float r[8];
    #pragma unroll
    for (int j = 0; j < 8; ++j) r[j] = sb2[q * 8 + j];
    #pragma unroll
    for (int k = 0; k < 16; ++k) {
        float a = sacc[g][k];
        const float* wrow = &sW[k * 32 + q * 8];
        #pragma unroll
        for (int j = 0; j < 8; ++j) r[j] = fmaf(a, wrow[j], r[j]);
    }
    if (nodeRaw < N_NODES) {
        f4v z = {0.f, 0.f, 0.f, 0.f};
        f4v o0 = {r[0], r[1], r[2], r[3]};
        f4v o1 = {r[4], r[5], r[6], r[7]};
        o0 = o0 > z ? o0 : z;
        o1 = o1 > z ? o1 : z;
        *reinterpret_cast<f4v*>(&out[nodeRaw * C2 + q * 8]) = o0;
        *reinterpret_cast<f4v*>(&out[nodeRaw * C2 + q * 8 + 4]) = o1;
    }
}

// ---------------- DDI branch (round-10 proven form: 4 rows/block) ----------------

#define DDI_CHUNK 132   // 1056 = 8 * 132

__global__ __launch_bounds__(256) void k_ddi(const float* __restrict__ feat,
                                             const float* __restrict__ fW1, const float* __restrict__ fb1,
                                             const float* __restrict__ fW2, const float* __restrict__ fb2,
                                             const float* __restrict__ fW3, const float* __restrict__ fb3,
                                             float* __restrict__ out) {
    __shared__ float sW[DDI_CHUNK * 64];
    __shared__ float sH[4][64];
    int tid = threadIdx.x;
    int wave = tid >> 6;
    int lane = tid & 63;
    int row = blockIdx.x * 4 + wave;

    float acc = 0.f;
    for (int k0 = 0; k0 < F_DDI; k0 += DDI_CHUNK) {
        __syncthreads();
        for (int idx = tid; idx < DDI_CHUNK * 64; idx += 256)
            sW[idx] = fW1[k0 * 64 + idx];
        __syncthreads();
        const float* frow = &feat[(size_t)row * F_DDI + k0];
        #pragma unroll 4
        for (int kk = 0; kk < DDI_CHUNK; kk += 4) {
            float4 fv = *reinterpret_cast<const float4*>(&frow[kk]);
            acc += fv.x * sW[(kk + 0) * 64 + lane];
            acc += fv.y * sW[(kk + 1) * 64 + lane];
            acc += fv.z * sW[(kk + 2) * 64 + lane];
            acc += fv.w * sW[(kk + 3) * 64 + lane];
        }
    }
    float h = fmaxf(acc + fb1[lane], 0.f);
    __syncthreads();
    sH[wave][lane] = h;
    __syncthreads();

    int c16 = lane & 15;
    float acc2 = 0.f;
    #pragma unroll
    for (int kk = 0; kk < 64; ++kk)
        acc2 += sH[wave][kk] * fW2[kk * 16 + c16];
    float o2 = fmaxf(acc2 + fb2[c16], 0.f);
    float part = o2 * fW3[c16];
    #pragma unroll
    for (int off = 8; off >= 1; off >>= 1)
        part += __shfl_xor(part, off, 16);
    if (lane == 0)
        out[row] = fmaxf(part + fb3[0], 0.f);
}

// ---------------- launch ----------------

extern "C" void kernel_launch(void* const* d_in, const int* in_sizes, int n_in,
                              void* d_out, int out_size, void* d_ws, size_t ws_size,
                              hipStream_t stream) {
    const float* x   = (const float*)d_in[0];
    const int*   ei  = (const int*)d_in[1];
    const float* ddi = (const float*)d_in[2];
    const float* W1  = (const float*)d_in[3];
    const float* b1  = (const float*)d_in[4];
    const float* W2  = (const float*)d_in[5];
    const float* b2  = (const float*)d_in[6];
    const float* fW1 = (const float*)d_in[7];
    const float* fb1 = (const float*)d_in[8];
    const float* fW2 = (const float*)d_in[9];
    const float* fb2 = (const float*)d_in[10];
    const float* fW3 = (const float*)d_in[11];
    const float* fb3 = (const float*)d_in[12];

    char* ws = (char*)d_ws;
    float* dinv  = (float*)(ws + O_DINV);
    int*   rp2   = (int*)(ws + O_RP2);
    int*   col   = (int*)(ws + O_COL);
    unsigned int* gbuf = (unsigned int*)(ws + O_GBUF);
    _Float16* h1s   = (_Float16*)(ws + O_H1);
    _Float16* out1s = (_Float16*)(ws + O_OUT1);
    int*   gcur  = (int*)(ws + O_GCUR);

    float* out_ppi = (float*)d_out;
    float* out_ddi = out_ppi + (size_t)N_NODES * C2;

    hipMemsetAsync(gcur, 0, NBUCK * sizeof(int), stream);
    k_bin<<<NB_BIN, 256, 0, stream>>>(ei, gcur, gbuf);
    k_place<<<NBUCK, 512, 0, stream>>>(gcur, gbuf, col, rp2, dinv);

    k_gemm1<<<(N_NODES + 63) / 64, 256, 0, stream>>>(x, W1, dinv, h1s);

    int gblk = (N_NODES * 4 + 255) / 256;
    k_gather1<<<gblk, 256, 0, stream>>>(rp2, col, dinv, h1s, b1, out1s);
    k_gather2<<<(N_NODES + 63) / 64, 256, 0, stream>>>(rp2, col, dinv, out1s, W2, b2, out_ppi);

    k_ddi<<<B_DDI / 4, 256, 0, stream>>>(ddi, fW1, fb1, fW2, fb2, fW3, fb3, out_ddi);
}